// Round 2
// baseline (298.142 us; speedup 1.0000x reference)
//
#include <hip/hip_runtime.h>
#include <hip/hip_fp16.h>
#include <cstdint>
#include <cstddef>

// DenseCaps dynamic routing, MI355X.
// B=256, R=2048, NC=10, OUT=16, IN=8, 3 routing iters.
//
// R2 analysis: passes were at the HBM roofline for the bytes they ISSUED,
// not the bytes they needed: lanes n=10..15 (6/16) loaded 32B each of
// dead u_hat data (37.5% wasted fetch), and bB added ~21MB/pass of
// amplified + dependent-load traffic. R2 fixes:
//  - U loads masked to n<10: each 16-lane group fetches exactly the 320B
//    row (64B-aligned, no waste).
//  - bB eliminated: b_k = b_in + dot(u, v0+..+v_{k-1}) (dot is linear in v).
//    Each pass rebuilds vsum in regs from the tiny s0..s2 buffers (inline
//    squash per block). P3 computes c and writes it straight to the output.
//  - grid 2048 (rr=8): 8 blocks/CU, 32 waves/CU for latency hiding.
// u_hat stays fp16 in ws ([r][b_local][160], produced coalesced via LDS
// transpose in uhat_kernel), batch processed in two halves of 128.

#define B_   256
#define R_   2048
#define NC_  10
#define OD_  16
#define IN_  8
#define BH_  128          // batch half
#define UROW 80           // dwords per (r,b) u_hat row (160 fp16)

__device__ __forceinline__ float rsum16(float x){
  x += __shfl_xor(x, 1, 16);
  x += __shfl_xor(x, 2, 16);
  x += __shfl_xor(x, 4, 16);
  x += __shfl_xor(x, 8, 16);
  return x;
}
__device__ __forceinline__ float rmax16(float x){
  x = fmaxf(x, __shfl_xor(x, 1, 16));
  x = fmaxf(x, __shfl_xor(x, 2, 16));
  x = fmaxf(x, __shfl_xor(x, 4, 16));
  x = fmaxf(x, __shfl_xor(x, 8, 16));
  return x;
}
__device__ __forceinline__ unsigned pack_f16(float a, float b){
  __half2 h = __floats2half2_rn(a, b);
  return *(unsigned*)&h;
}
__device__ __forceinline__ void unpack8(uint4 d, float* f){
  float2 t;
  t = __half22float2(*(__half2*)&d.x); f[0] = t.x; f[1] = t.y;
  t = __half22float2(*(__half2*)&d.y); f[2] = t.x; f[3] = t.y;
  t = __half22float2(*(__half2*)&d.z); f[4] = t.x; f[5] = t.y;
  t = __half22float2(*(__half2*)&d.w); f[6] = t.x; f[7] = t.y;
}
// vreg += squash(s[b, nn*16 .. +16])
__device__ __forceinline__ void add_squash(float* vreg, const float* __restrict__ s,
                                           int b, int nn){
  const float* sp = s + b * 160 + nn * 16;
  float t[16]; float ss = 0.f;
  #pragma unroll
  for (int o = 0; o < 16; ++o){ t[o] = sp[o]; ss = fmaf(t[o], t[o], ss); }
  float f = sqrtf(ss) / (1.f + ss + 1e-8f);
  #pragma unroll
  for (int o = 0; o < 16; ++o) vreg[o] = fmaf(f, t[o], vreg[o]);
}

// ---------- u_hat producer: one block per route r, one batch-half ----------
// thread = (nh in {0,1}, bl in [0,128)): computes the 80 outputs (5 classes)
// of (b0+bl, r) for column-half nh. W[r] staged in LDS (broadcast reads).
// Results held in 40 VGPRs, transposed through LDS (44-dword rows), flushed
// as fully coalesced dwordx4 stores.
__global__ __launch_bounds__(256) void uhat_kernel(const float* __restrict__ x,
                                                   const float* __restrict__ W,
                                                   uint32_t* __restrict__ U,
                                                   int b0){
  const int r = blockIdx.x;
  __shared__ float Wl[IN_ * 160];        // 5 KB
  __shared__ uint32_t St[256 * 44];      // 45 KB transpose staging
  {
    const float4* Wg = (const float4*)(W + (size_t)r * (IN_ * 160));
    float4* Wl4 = (float4*)Wl;
    for (int i = threadIdx.x; i < 320; i += 256) Wl4[i] = Wg[i];
  }
  __syncthreads();
  const int nh = threadIdx.x >> 7;
  const int bl = threadIdx.x & 127;
  const float4* xp = (const float4*)(x + ((size_t)(b0 + bl) * R_ + r) * IN_);
  float4 xa = xp[0], xb = xp[1];
  float xr[8] = {xa.x, xa.y, xa.z, xa.w, xb.x, xb.y, xb.z, xb.w};
  const float4* Wl4 = (const float4*)Wl;
  uint32_t res[40];
  #pragma unroll
  for (int co = 0; co < 20; ++co){
    float4 u = make_float4(0.f, 0.f, 0.f, 0.f);
    #pragma unroll
    for (int i = 0; i < 8; ++i){
      float4 w = Wl4[i * 40 + nh * 20 + co];   // wave-uniform addr: broadcast
      u.x = fmaf(xr[i], w.x, u.x);
      u.y = fmaf(xr[i], w.y, u.y);
      u.z = fmaf(xr[i], w.z, u.z);
      u.w = fmaf(xr[i], w.w, u.w);
    }
    res[2 * co]     = pack_f16(u.x, u.y);
    res[2 * co + 1] = pack_f16(u.z, u.w);
  }
  {
    uint4* row = (uint4*)(St + threadIdx.x * 44);
    #pragma unroll
    for (int k = 0; k < 10; ++k)
      row[k] = make_uint4(res[4*k], res[4*k+1], res[4*k+2], res[4*k+3]);
  }
  __syncthreads();
  uint4* dst = (uint4*)(U + (size_t)r * (BH_ * UROW));
  #pragma unroll
  for (int k2 = 0; k2 < 10; ++k2){
    int f    = k2 * 256 + threadIdx.x;   // 0..2559
    int tp   = f / 10;
    int kk   = f - tp * 10;
    int srow = (tp >> 1) + (tp & 1) * 128;
    dst[f] = *(const uint4*)(St + srow * 44 + kk * 4);
  }
}

// ---------- fused routing pass ----------
// MODE 0: c = softmax(b_in[r]);                      s0 += c*u
// MODE 1: vsum=v0;        c=softmax(b_in+dot);       s1 += c*u
// MODE 2: vsum=v0+v1;     c=softmax(b_in+dot);       s2 += c*u
// MODE 3: vsum=v0+v1+v2;  c=softmax(b_in+dot) -> out; s3 += c*u
// grid = 128 b_local x 16 r-chunks; thread = (rs in 16, n-lane in 16).
template<int MODE>
__global__ __launch_bounds__(256) void pass_kernel(
    const uint32_t* __restrict__ U,     // [R][BH][80] dwords (fp16 u_hat)
    const float*    __restrict__ b_in,  // [R][NC]
    float*          __restrict__ c_out, // [B][R][NC] (output c region)
    const float*    __restrict__ s0,
    const float*    __restrict__ s1,
    const float*    __restrict__ s2,
    float*          __restrict__ s_out,
    int b0)
{
  const int bl = blockIdx.x >> 4;       // 0..127
  const int b  = b0 + bl;
  const int rc = blockIdx.x & 15;       // 0..15
  const int n  = threadIdx.x & 15;
  const int rs = threadIdx.x >> 4;
  const int nn = (n < NC_) ? n : (NC_ - 1);

  float vreg[16];
  #pragma unroll
  for (int o = 0; o < 16; ++o) vreg[o] = 0.f;
  if (MODE >= 1) add_squash(vreg, s0, b, nn);
  if (MODE >= 2) add_squash(vreg, s1, b, nn);
  if (MODE >= 3) add_squash(vreg, s2, b, nn);

  float acc[16];
  #pragma unroll
  for (int o = 0; o < 16; ++o) acc[o] = 0.f;

  const int r0 = rc * 128;
  for (int rr = 0; rr < 8; ++rr){
    const int r = r0 + rr * 16 + rs;
    float uf[16];
    #pragma unroll
    for (int o = 0; o < 16; ++o) uf[o] = 0.f;
    if (n < NC_){
      // 10 active lanes fetch exactly the 320B row (64B-aligned, no waste)
      const uint4* up = (const uint4*)(U + ((size_t)r * BH_ + bl) * UROW + n * 8);
      uint4 ua = up[0], ub = up[1];
      unpack8(ua, uf);
      unpack8(ub, uf + 8);
    }
    float t = 0.f;
    if (MODE != 0){
      #pragma unroll
      for (int o = 0; o < 16; ++o) t = fmaf(uf[o], vreg[o], t);
    }
    float bold = b_in[r * NC_ + nn];
    float bnew = (n < NC_) ? (bold + t) : -1e30f;
    float m = rmax16(bnew);
    float e = __expf(bnew - m);            // idle lanes -> 0
    float sum = rsum16(e);
    float c = e / sum;
    if (MODE == 3 && n < NC_) c_out[((size_t)b * R_ + r) * NC_ + n] = c;
    #pragma unroll
    for (int o = 0; o < 16; ++o) acc[o] = fmaf(c, uf[o], acc[o]);
  }

  // block reduction over the 16 rs partials, then one atomic per (n,o)
  __shared__ float sd[16 * 16 * 17];
  #pragma unroll
  for (int o = 0; o < 16; ++o) sd[rs * 272 + n * 17 + o] = acc[o];
  __syncthreads();
  const int n2 = threadIdx.x >> 4;
  const int o2 = threadIdx.x & 15;
  if (n2 < NC_){
    float tot = 0.f;
    #pragma unroll
    for (int k = 0; k < 16; ++k) tot += sd[k * 272 + n2 * 17 + o2];
    atomicAdd(&s_out[b * 160 + n2 * 16 + o2], tot);
  }
}

// ---------- final squash: v_out = squash(s3) ----------
__global__ __launch_bounds__(256) void squash_final(const float* __restrict__ s,
                                                    float* __restrict__ vout){
  int g = blockIdx.x * 256 + threadIdx.x;   // 16 lanes per (b,n) row
  float xv = s[g];
  float ss = rsum16(xv * xv);
  float norm = sqrtf(ss);
  vout[g] = (norm / (1.f + ss + 1e-8f)) * xv;
}

extern "C" void kernel_launch(void* const* d_in, const int* in_sizes, int n_in,
                              void* d_out, int out_size, void* d_ws, size_t ws_size,
                              hipStream_t stream){
  const float* x    = (const float*)d_in[0];   // [256,2048,8]
  const float* W    = (const float*)d_in[1];   // [2048,8,160]
  const float* b_in = (const float*)d_in[2];   // [2048,10]
  float* out = (float*)d_out;
  float* out_v = out;                 // 40960 floats
  float* c_out = out + 40960;         // [B][R][NC] final coupling coeffs

  char* w = (char*)d_ws;
  uint32_t* U = (uint32_t*)w;                      // 2048*128*80*4 = 83,886,080 B
  float* s0 = (float*)(w + 83886080);              // 4 x 163,840 B s-chain
  float* s1 = s0 + 40960;
  float* s2 = s1 + 40960;
  float* s3 = s2 + 40960;

  hipMemsetAsync(s0, 0, 4 * 40960 * sizeof(float), stream);
  for (int h = 0; h < 2; ++h){
    const int b0 = h * BH_;
    uhat_kernel<<<R_, 256, 0, stream>>>(x, W, U, b0);
    pass_kernel<0><<<2048, 256, 0, stream>>>(U, b_in, c_out, s0, s1, s2, s0, b0);
    pass_kernel<1><<<2048, 256, 0, stream>>>(U, b_in, c_out, s0, s1, s2, s1, b0);
    pass_kernel<2><<<2048, 256, 0, stream>>>(U, b_in, c_out, s0, s1, s2, s2, b0);
    pass_kernel<3><<<2048, 256, 0, stream>>>(U, b_in, c_out, s0, s1, s2, s3, b0);
  }
  squash_final<<<160, 256, 0, stream>>>(s3, out_v);
}